// Round 14
// baseline (72.860 us; speedup 1.0000x reference)
//
#include <hip/hip_runtime.h>
#include <hip/hip_bf16.h>

#define N_NODES 100000
#define T_DIM 64
#define D_DIM 128
#define M_MATS 8
#define CROSS_PRUNE 0.1f
#define MSTRIDE (T_DIM * D_DIM)   // 8192: one mat

typedef __attribute__((ext_vector_type(8))) short bf16x8;    // MFMA A/B fragment
typedef __attribute__((ext_vector_type(4))) float f32x4;     // MFMA accumulator
typedef __attribute__((ext_vector_type(8))) unsigned short ushort8;

// RNE 3-level split via native casts. r1 = v - bf(v), r2 = r1 - bf(r1) exact (Sterbenz).
__device__ __forceinline__ void split3(float v, unsigned short& h,
                                       unsigned short& m, unsigned short& l) {
    __hip_bfloat16 bh = __float2bfloat16(v);
    float fh = __bfloat162float(bh);
    float r1 = v - fh;
    __hip_bfloat16 bm = __float2bfloat16(r1);
    float fm = __bfloat162float(bm);
    float r2 = r1 - fm;
    __hip_bfloat16 bl = __float2bfloat16(r2);
    h = __builtin_bit_cast(unsigned short, bh);
    m = __builtin_bit_cast(unsigned short, bm);
    l = __builtin_bit_cast(unsigned short, bl);
}

// ---- Single fused kernel: per-block W prologue + R6-exact MFMA cross ----
// 1563 blocks x 256 thr (4 waves); block owns 64 n; wave tg owns t [tg*16,+16).
// W fragments: each thread reduces its own 32 W elems over the 8 mats (L2-hot,
// 64 independent dwordx4 loads) and 3-level-splits them -> ah/am/al[4].
// x: two-half staging into 3 LDS planes [64][64] bf16 (24 KB), XOR-swizzled
// byte ^= (row&7)<<4 (ushort8 writes AND b128 reads at the 8/bank floor).
// 6-product split MFMA (hh,hm,mh,hl,lh,mm), paired-nt (acc reuse distance 2).
__global__ __launch_bounds__(256, 4) void fused_kernel(const float* __restrict__ x,
                                                       const float* __restrict__ mats,
                                                       const float* __restrict__ head_w,
                                                       const float* __restrict__ head_b_p,
                                                       float* __restrict__ out) {
    __shared__ unsigned short xh[64 * 64];
    __shared__ unsigned short xm[64 * 64];
    __shared__ unsigned short xl[64 * 64];

    const int tid = threadIdx.x;
    const int n0 = blockIdx.x * 64;
    const int lane = tid & 63;
    const int tg = tid >> 6;    // wave's t-group
    const int r = lane & 15;    // A row / B col within 16
    const int q = lane >> 4;    // k sub-block / C row group
    const int srow = tid >> 2;  // staging row
    const int scol = (tid & 3) * 16;

    // ---- x global loads FIRST (HBM latency hides under W prologue) ----
    float4 p0[4], p1[4];
    {
        const int gn = n0 + srow;
        const float* xrow = x + (size_t)gn * D_DIM + scol;
#pragma unroll
        for (int j = 0; j < 4; ++j) {
            p0[j] = make_float4(0.f, 0.f, 0.f, 0.f);
            p1[j] = p0[j];
            if (gn < N_NODES) {
                p0[j] = *reinterpret_cast<const float4*>(xrow + j * 4);        // half 0
                p1[j] = *reinterpret_cast<const float4*>(xrow + 64 + j * 4);   // half 1
            }
        }
    }

    // ---- W prologue: reduce over mats (L2-hot), split 3-level ----
    float hw[M_MATS];
#pragma unroll
    for (int m = 0; m < M_MATS; ++m) hw[m] = head_w[m];   // uniform -> s_load

    bf16x8 ah[4], am[4], al[4];
#pragma unroll
    for (int k4 = 0; k4 < 4; ++k4) {
        const float* wp = mats + (tg * 16 + r) * D_DIM + k4 * 32 + q * 8;
        float wa[8];
#pragma unroll
        for (int e = 0; e < 8; ++e) wa[e] = 0.f;
#pragma unroll
        for (int m = 0; m < M_MATS; ++m) {
            float4 v0 = *reinterpret_cast<const float4*>(wp + m * MSTRIDE);
            float4 v1 = *reinterpret_cast<const float4*>(wp + m * MSTRIDE + 4);
            wa[0] = fmaf(hw[m], v0.x, wa[0]); wa[1] = fmaf(hw[m], v0.y, wa[1]);
            wa[2] = fmaf(hw[m], v0.z, wa[2]); wa[3] = fmaf(hw[m], v0.w, wa[3]);
            wa[4] = fmaf(hw[m], v1.x, wa[4]); wa[5] = fmaf(hw[m], v1.y, wa[5]);
            wa[6] = fmaf(hw[m], v1.z, wa[6]); wa[7] = fmaf(hw[m], v1.w, wa[7]);
        }
#pragma unroll
        for (int e = 0; e < 8; ++e) {
            unsigned short h_, m_, l_;
            split3(wa[e], h_, m_, l_);
            ah[k4][e] = (short)h_; am[k4][e] = (short)m_; al[k4][e] = (short)l_;
        }
    }
    const float hb = head_b_p[0];

    // split 16 elems and store as 2 swizzled ushort8 per plane (R6-verified)
#define SPLIT_STORE16(P)                                                        \
    {                                                                           \
        float fv[16];                                                           \
        _Pragma("unroll")                                                       \
        for (int j = 0; j < 4; ++j) {                                           \
            fv[j * 4 + 0] = (P)[j].x; fv[j * 4 + 1] = (P)[j].y;                 \
            fv[j * 4 + 2] = (P)[j].z; fv[j * 4 + 3] = (P)[j].w;                 \
        }                                                                       \
        _Pragma("unroll")                                                       \
        for (int u = 0; u < 2; ++u) {                                           \
            ushort8 H, M, L;                                                    \
            _Pragma("unroll")                                                   \
            for (int e = 0; e < 8; ++e) {                                       \
                unsigned short h_, m_, l_;                                      \
                split3(fv[u * 8 + e], h_, m_, l_);                              \
                H[e] = h_; M[e] = m_; L[e] = l_;                                \
            }                                                                   \
            int unit = srow * 8 + (tid & 3) * 2 + u;                            \
            int byte = (unit << 4) ^ ((srow & 7) << 4);                         \
            *reinterpret_cast<ushort8*>(reinterpret_cast<char*>(xh) + byte) = H;\
            *reinterpret_cast<ushort8*>(reinterpret_cast<char*>(xm) + byte) = M;\
            *reinterpret_cast<ushort8*>(reinterpret_cast<char*>(xl) + byte) = L;\
        }                                                                       \
    }

    SPLIT_STORE16(p0);
    __syncthreads();

    f32x4 acc[4];
#pragma unroll
    for (int nt = 0; nt < 4; ++nt) acc[nt] = (f32x4){0.f, 0.f, 0.f, 0.f};

#pragma unroll
    for (int half = 0; half < 2; ++half) {
        if (half == 1) {
            __syncthreads();   // half-0 readers done
            SPLIT_STORE16(p1);
            __syncthreads();
        }

        // ---- MFMA: per k4, nt in pairs (acc reuse distance 2) — R6/R8 order ----
#pragma unroll
        for (int kk = 0; kk < 2; ++kk) {
            const bf16x8 Ah = ah[half * 2 + kk];
            const bf16x8 Am = am[half * 2 + kk];
            const bf16x8 Al = al[half * 2 + kk];
#pragma unroll
            for (int np = 0; np < 4; np += 2) {
                int e0 = ((np * 16 + r) * 64 + kk * 32 + q * 8);
                int b0 = (e0 << 1) ^ ((r & 7) << 4);
                int e1 = (((np + 1) * 16 + r) * 64 + kk * 32 + q * 8);
                int b1 = (e1 << 1) ^ ((r & 7) << 4);
                bf16x8 bh0 = *reinterpret_cast<const bf16x8*>(reinterpret_cast<const char*>(xh) + b0);
                bf16x8 bm0 = *reinterpret_cast<const bf16x8*>(reinterpret_cast<const char*>(xm) + b0);
                bf16x8 bl0 = *reinterpret_cast<const bf16x8*>(reinterpret_cast<const char*>(xl) + b0);
                bf16x8 bh1 = *reinterpret_cast<const bf16x8*>(reinterpret_cast<const char*>(xh) + b1);
                bf16x8 bm1 = *reinterpret_cast<const bf16x8*>(reinterpret_cast<const char*>(xm) + b1);
                bf16x8 bl1 = *reinterpret_cast<const bf16x8*>(reinterpret_cast<const char*>(xl) + b1);
                acc[np]     = __builtin_amdgcn_mfma_f32_16x16x32_bf16(Ah, bh0, acc[np], 0, 0, 0);
                acc[np + 1] = __builtin_amdgcn_mfma_f32_16x16x32_bf16(Ah, bh1, acc[np + 1], 0, 0, 0);
                acc[np]     = __builtin_amdgcn_mfma_f32_16x16x32_bf16(Ah, bm0, acc[np], 0, 0, 0);
                acc[np + 1] = __builtin_amdgcn_mfma_f32_16x16x32_bf16(Ah, bm1, acc[np + 1], 0, 0, 0);
                acc[np]     = __builtin_amdgcn_mfma_f32_16x16x32_bf16(Am, bh0, acc[np], 0, 0, 0);
                acc[np + 1] = __builtin_amdgcn_mfma_f32_16x16x32_bf16(Am, bh1, acc[np + 1], 0, 0, 0);
                acc[np]     = __builtin_amdgcn_mfma_f32_16x16x32_bf16(Ah, bl0, acc[np], 0, 0, 0);
                acc[np + 1] = __builtin_amdgcn_mfma_f32_16x16x32_bf16(Ah, bl1, acc[np + 1], 0, 0, 0);
                acc[np]     = __builtin_amdgcn_mfma_f32_16x16x32_bf16(Al, bh0, acc[np], 0, 0, 0);
                acc[np + 1] = __builtin_amdgcn_mfma_f32_16x16x32_bf16(Al, bh1, acc[np + 1], 0, 0, 0);
                acc[np]     = __builtin_amdgcn_mfma_f32_16x16x32_bf16(Am, bm0, acc[np], 0, 0, 0);
                acc[np + 1] = __builtin_amdgcn_mfma_f32_16x16x32_bf16(Am, bm1, acc[np + 1], 0, 0, 0);
            }
        }
    }

    // ---- epilogue: sigmoid + prune + store (C: col=r -> n, row=q*4+i -> t) ----
#pragma unroll
    for (int nt = 0; nt < 4; ++nt) {
        int n = n0 + nt * 16 + r;
        if (n < N_NODES) {
#pragma unroll
            for (int i = 0; i < 4; ++i) {
                int t = tg * 16 + q * 4 + i;
                float v = acc[nt][i] + hb;
                float s = 1.0f / (1.0f + __expf(-v));
                if (s < CROSS_PRUNE) s = 0.0f;
                out[(size_t)t * N_NODES + n] = s;
            }
        }
    }
#undef SPLIT_STORE16
}

extern "C" void kernel_launch(void* const* d_in, const int* in_sizes, int n_in,
                              void* d_out, int out_size, void* d_ws, size_t ws_size,
                              hipStream_t stream) {
    const float* x      = (const float*)d_in[0];  // [N, D]
    const float* mats   = (const float*)d_in[1];  // [M, T, D]
    const float* head_w = (const float*)d_in[2];  // [M]
    const float* head_b = (const float*)d_in[3];  // [] (1 element)
    float* out = (float*)d_out;                   // [T, N] f32

    int nblk = (N_NODES + 63) / 64;   // 1563
    hipLaunchKernelGGL(fused_kernel, dim3(nblk), dim3(256), 0, stream,
                       x, mats, head_w, head_b, out);
}